// Round 10
// baseline (87.767 us; speedup 1.0000x reference)
//
#include <hip/hip_runtime.h>
#include <hip/hip_bf16.h>
#include <math.h>

// Problem constants
#define BB 8
#define SS 2048
#define DD 256
#define FF 8
#define NTOK (BB*SS)   // 16384

typedef __bf16 bf16x8 __attribute__((ext_vector_type(8)));
typedef float  f32x4  __attribute__((ext_vector_type(4)));
typedef float  f32x2  __attribute__((ext_vector_type(2)));

// ---------------- Kernel A: h = tanh(x @ W1^T + b1) -> fp8(e4m3) table via MFMA ----------
// R17. Session model (fits R4/R10/R14/R15/R16): A_time ~ total staged bytes / ~7 TB/s.
//   R4=R15=R16 all stage 512x192KB = 96 MB -> all ~13.5us (tile flips are a no-op!).
//   R10 staged 48 MB -> 8.4us (but +9.5us extra dispatch). L2/L3 dedup of redundant
//   reads never materializes; only arithmetic reduction of staged bytes helps.
// R17: BM=BN=128 -> 256 blocks x 256 KB = 64 MB staged (2/3 of R15). LDS = exactly
// 64 KB (no pad; R10-proven XOR-granule swizzle kills bank conflicts instead).
// Grid 256 = 1 block/CU, 8 waves, launch_bounds(512,2) -> no spill risk.
// Ledger: scattered direct-to-frag loads +16us (R8/R12); grid.sync ~100us (R11);
// W-chunk-serialized variants A~17us (R13/R14). Keep the R4/R15 dbuf pipeline shape.
#define BM 128
#define BN 128
#define BK 64
#define NSTEP (DD/BK)   // 4

__device__ __forceinline__ float fast_tanh(float x) {
    float e = __expf(2.0f * x);
    return 1.0f - 2.0f * __builtin_amdgcn_rcpf(e + 1.0f);
}

__device__ __forceinline__ unsigned pack2_bf16(float a, float b) {
    return (__float_as_uint(a) >> 16) | (__float_as_uint(b) & 0xFFFF0000u);
}

__device__ __forceinline__ unsigned char f32_to_fp8(float v) {
    return (unsigned char)(__builtin_amdgcn_cvt_pk_fp8_f32(v, v, 0, false) & 0xFF);
}

__global__ __launch_bounds__(512, 2) void gemm_tanh_kernel(
    const float* __restrict__ x, const float* __restrict__ W1,
    const float* __restrict__ b1, unsigned char* __restrict__ table)
{
    // 128 rows x 64 ushorts (128 B) per buffer, XOR-swizzled granules, no padding.
    __shared__ __align__(16) unsigned short xs[2][BM * 64];   // 32 KB (reused as scratch)
    __shared__ __align__(16) unsigned short wsb[2][BN * 64];  // 32 KB

    const int tid  = threadIdx.x;
    const int bx   = blockIdx.x;
    // decode: bx = g*16 + n*8 + x -> the 2 n-siblings of a token group are 8 apart
    const int tokgrp = ((bx >> 4) << 3) | (bx & 7);   // 0..127
    const int nblk   = (bx >> 3) & 1;                 // 0..1
    const int tok0 = tokgrp * BM;
    const int n0   = nblk * BN;

    // re-zero padding row 0 (256 fp8 bytes); ws is re-poisoned before every launch
    if (bx == 0 && tid < 64) ((unsigned int*)table)[tid] = 0u;

    const int wave = tid >> 6, lane = tid & 63;
    const int wm = wave >> 1;        // 0..3: 32-row m band
    const int wn = wave & 1;         // 0..1: 64-col n band
    const int lr = lane & 15;
    const int kg = lane >> 4;
    const int sw = lr & 7;           // swizzle key == (row&7) for all frag rows this lane reads

    f32x4 xr[4], wr[4];              // staging registers

    auto load_chunk = [&](int k0) {
        #pragma unroll
        for (int rep = 0; rep < 4; ++rep) {            // x: 128 rows x 16 f32x4 = 2048 slots
            int slot = rep * 512 + tid;
            int row = slot >> 4, kc = slot & 15;
            xr[rep] = *(const f32x4*)&x[(size_t)(tok0 + row) * DD + k0 + kc * 4];
        }
        #pragma unroll
        for (int rep = 0; rep < 4; ++rep) {            // W1: 128 rows x 16 f32x4 = 2048 slots
            int slot = rep * 512 + tid;
            int row = slot >> 4, kc = slot & 15;
            wr[rep] = *(const f32x4*)&W1[(size_t)(n0 + row) * DD + k0 + kc * 4];
        }
    };
    auto store_lds = [&](int buf) {
        #pragma unroll
        for (int rep = 0; rep < 4; ++rep) {
            int slot = rep * 512 + tid;
            int row = slot >> 4, kc = slot & 15;
            uint2 p;
            p.x = pack2_bf16(xr[rep].x, xr[rep].y);
            p.y = pack2_bf16(xr[rep].z, xr[rep].w);
            int gp = (kc >> 1) ^ (row & 7);            // XOR-swizzled 16B granule (0..7)
            *(uint2*)&xs[buf][row * 64 + gp * 8 + (kc & 1) * 4] = p;
        }
        #pragma unroll
        for (int rep = 0; rep < 4; ++rep) {
            int slot = rep * 512 + tid;
            int row = slot >> 4, kc = slot & 15;
            uint2 p;
            p.x = pack2_bf16(wr[rep].x, wr[rep].y);
            p.y = pack2_bf16(wr[rep].z, wr[rep].w);
            int gp = (kc >> 1) ^ (row & 7);
            *(uint2*)&wsb[buf][row * 64 + gp * 8 + (kc & 1) * 4] = p;
        }
    };

    f32x4 acc[2][4];
    #pragma unroll
    for (int mf = 0; mf < 2; ++mf)
        #pragma unroll
        for (int nf = 0; nf < 4; ++nf)
            acc[mf][nf] = (f32x4){0.f, 0.f, 0.f, 0.f};

    load_chunk(0);
    store_lds(0);

    for (int s = 0; s < NSTEP; ++s) {
        __syncthreads();                               // one barrier per step
        const int buf = s & 1;
        if (s + 1 < NSTEP) load_chunk((s + 1) * BK);   // global loads in flight early

        #pragma unroll
        for (int c = 0; c < 2; ++c) {                  // per-k-chunk to limit live frags
            int gp8 = ((c * 4 + kg) ^ sw) * 8;
            bf16x8 af[2], bfr[4];
            #pragma unroll
            for (int mf = 0; mf < 2; ++mf) {
                int m = wm * 32 + mf * 16 + lr;
                af[mf] = *(const bf16x8*)&xs[buf][m * 64 + gp8];
            }
            #pragma unroll
            for (int nf = 0; nf < 4; ++nf) {
                int n = wn * 64 + nf * 16 + lr;
                bfr[nf] = *(const bf16x8*)&wsb[buf][n * 64 + gp8];
            }
            #pragma unroll
            for (int mf = 0; mf < 2; ++mf)
                #pragma unroll
                for (int nf = 0; nf < 4; ++nf)
                    acc[mf][nf] = __builtin_amdgcn_mfma_f32_16x16x32_bf16(
                        af[mf], bfr[nf], acc[mf][nf], 0, 0, 0);
        }
        if (s + 1 < NSTEP) store_lds(buf ^ 1);         // buf^1 reads drained at this step's barrier
    }

    // ---- epilogue: bias + tanh -> fp8, LDS transpose, coalesced stores ----
    float bj[4];
    #pragma unroll
    for (int nf = 0; nf < 4; ++nf) bj[nf] = b1[n0 + wn * 64 + nf * 16 + lr];

    __syncthreads();                                   // safe to reuse xs as scratch
    unsigned char* sc = (unsigned char*)&xs[0][0];     // [128][136] fp8 scratch (17.4 KB)
    #pragma unroll
    for (int mf = 0; mf < 2; ++mf) {
        #pragma unroll
        for (int r = 0; r < 4; ++r) {
            int m = wm * 32 + mf * 16 + kg * 4 + r;    // C/D layout: col=lane&15, row=kg*4+reg
            #pragma unroll
            for (int nf = 0; nf < 4; ++nf) {
                float v = fast_tanh(acc[mf][nf][r] + bj[nf]);
                sc[m * 136 + wn * 64 + nf * 16 + lr] = f32_to_fp8(v);
            }
        }
    }
    __syncthreads();
    {
        int row = tid >> 2;                            // 128 rows x 128 B, 32 B per thread
        int off = (tid & 3) * 32;
        uint4 v0 = *(const uint4*)&sc[row * 136 + off];
        uint4 v1 = *(const uint4*)&sc[row * 136 + off + 16];
        *(uint4*)&table[(size_t)(1 + tok0 + row) * DD + n0 + off]      = v0;
        *(uint4*)&table[(size_t)(1 + tok0 + row) * DD + n0 + off + 16] = v1;
    }
}

// ---------------- Kernel B: fp8 gather + max over F + dot(w2) + bias + mask ----------------
// R14-verified: 2048 blocks; each wave handles TWO tokens with all 8 gather loads
// interleaved -> 2x memory-level parallelism, half the block count.
__global__ __launch_bounds__(256) void gather_score_kernel(
    const unsigned char* __restrict__ table,
    const int* __restrict__ select_idx,
    const int* __restrict__ word_mask,
    const float* __restrict__ w2,
    const float* __restrict__ b2,
    float* __restrict__ out)
{
    const int tid  = threadIdx.x;
    const int lane = tid & 63;
    const int wv   = tid >> 6;
    const int iA   = blockIdx.x * 8 + wv * 2;     // tokens iA, iA+1
    const int iB   = iA + 1;
    const int half = lane >> 5;
    const int c    = lane & 31;
    const int d0   = c * 8;                        // 8 dims (8 B) per lane

    const int4* spA = (const int4*)(select_idx + (size_t)iA * FF);
    const int4* spB = (const int4*)(select_idx + (size_t)iB * FF);
    int4 qa0 = spA[0], qa1 = spA[1];
    int4 qb0 = spB[0], qb1 = spB[1];
    int rA[4], rB[4];
    rA[0] = half ? qa0.y : qa0.x;  rA[1] = half ? qa0.w : qa0.z;
    rA[2] = half ? qa1.y : qa1.x;  rA[3] = half ? qa1.w : qa1.z;
    rB[0] = half ? qb0.y : qb0.x;  rB[1] = half ? qb0.w : qb0.z;
    rB[2] = half ? qb1.y : qb1.x;  rB[3] = half ? qb1.w : qb1.z;

    uint2 uA[4], uB[4];                            // all 8 gathers in flight together
    #pragma unroll
    for (int it = 0; it < 4; ++it) {
        uA[it] = *(const uint2*)(table + (size_t)rA[it] * DD + d0);
        uB[it] = *(const uint2*)(table + (size_t)rB[it] * DD + d0);
    }

    float mA[8], mB[8];
    #pragma unroll
    for (int j = 0; j < 8; ++j) { mA[j] = -INFINITY; mB[j] = -INFINITY; }

    #pragma unroll
    for (int it = 0; it < 4; ++it) {
        f32x2 a0 = __builtin_amdgcn_cvt_pk_f32_fp8(uA[it].x, false);
        f32x2 a1 = __builtin_amdgcn_cvt_pk_f32_fp8(uA[it].x, true);
        f32x2 a2 = __builtin_amdgcn_cvt_pk_f32_fp8(uA[it].y, false);
        f32x2 a3 = __builtin_amdgcn_cvt_pk_f32_fp8(uA[it].y, true);
        mA[0] = fmaxf(mA[0], a0.x); mA[1] = fmaxf(mA[1], a0.y);
        mA[2] = fmaxf(mA[2], a1.x); mA[3] = fmaxf(mA[3], a1.y);
        mA[4] = fmaxf(mA[4], a2.x); mA[5] = fmaxf(mA[5], a2.y);
        mA[6] = fmaxf(mA[6], a3.x); mA[7] = fmaxf(mA[7], a3.y);
        f32x2 b0 = __builtin_amdgcn_cvt_pk_f32_fp8(uB[it].x, false);
        f32x2 b1v = __builtin_amdgcn_cvt_pk_f32_fp8(uB[it].x, true);
        f32x2 b2v = __builtin_amdgcn_cvt_pk_f32_fp8(uB[it].y, false);
        f32x2 b3 = __builtin_amdgcn_cvt_pk_f32_fp8(uB[it].y, true);
        mB[0] = fmaxf(mB[0], b0.x); mB[1] = fmaxf(mB[1], b0.y);
        mB[2] = fmaxf(mB[2], b1v.x); mB[3] = fmaxf(mB[3], b1v.y);
        mB[4] = fmaxf(mB[4], b2v.x); mB[5] = fmaxf(mB[5], b2v.y);
        mB[6] = fmaxf(mB[6], b3.x); mB[7] = fmaxf(mB[7], b3.y);
    }

    #pragma unroll
    for (int j = 0; j < 8; ++j) {
        mA[j] = fmaxf(mA[j], __shfl_xor(mA[j], 32));
        mB[j] = fmaxf(mB[j], __shfl_xor(mB[j], 32));
    }

    f32x4 wa = *(const f32x4*)&w2[d0];
    f32x4 wb = *(const f32x4*)&w2[d0 + 4];
    float pA = mA[0] * wa.x + mA[1] * wa.y + mA[2] * wa.z + mA[3] * wa.w
             + mA[4] * wb.x + mA[5] * wb.y + mA[6] * wb.z + mA[7] * wb.w;
    float pB = mB[0] * wa.x + mB[1] * wa.y + mB[2] * wa.z + mB[3] * wa.w
             + mB[4] * wb.x + mB[5] * wb.y + mB[6] * wb.z + mB[7] * wb.w;

    #pragma unroll
    for (int off = 16; off; off >>= 1) {
        pA += __shfl_xor(pA, off);
        pB += __shfl_xor(pB, off);
    }

    if (lane == 0) {
        float negA = word_mask[iA] ? 0.f : -10000.f;
        float negB = word_mask[iB] ? 0.f : -10000.f;
        out[iA] = pA + b2[0] + negA;
        out[iB] = pB + b2[0] + negB;
    }
}

extern "C" void kernel_launch(void* const* d_in, const int* in_sizes, int n_in,
                              void* d_out, int out_size, void* d_ws, size_t ws_size,
                              hipStream_t stream) {
    const float* hs    = (const float*)d_in[0];   // [B,S,D] f32
    const int*   sidx  = (const int*)  d_in[1];   // [B,S,F] i32
    const int*   wmask = (const int*)  d_in[2];   // [B,S]   i32
    const float* W1    = (const float*)d_in[3];   // [D,D]   f32
    const float* b1    = (const float*)d_in[4];   // [D]     f32
    const float* w2    = (const float*)d_in[5];   // [D]     f32
    const float* b2    = (const float*)d_in[6];   // [1]     f32
    float* out = (float*)d_out;                   // [B,S]   f32

    unsigned char* table = (unsigned char*)d_ws;  // [1+NTOK, D] fp8 e4m3 (~4.2 MB)

    gemm_tanh_kernel<<<(NTOK / BM) * (DD / BN), 512, 0, stream>>>(hs, W1, b1, table);
    gather_score_kernel<<<NTOK / 8, 256, 0, stream>>>(table, sidx, wmask, w2, b2, out);
}

// Round 11
// 86.754 us; speedup vs baseline: 1.0117x; 1.0117x over previous
//
#include <hip/hip_runtime.h>
#include <hip/hip_bf16.h>
#include <math.h>

// Problem constants
#define BB 8
#define SS 2048
#define DD 256
#define FF 8
#define NTOK (BB*SS)   // 16384

typedef __bf16 bf16x8 __attribute__((ext_vector_type(8)));
typedef float  f32x4  __attribute__((ext_vector_type(4)));
typedef float  f32x2  __attribute__((ext_vector_type(2)));

// ---------------- Kernel A: h = tanh(x @ W1^T + b1) -> fp8(e4m3) table via MFMA ----------
// R18. Session invariant: ALL LDS-staged dbuf variants (R4/R15/R16/R17) give A~13.5us
// regardless of tile shape / staged bytes (96 or 64 MB) / sibling decode. Staged-bytes
// model falsified by R17; occupancy is the remaining suspect: R17 ran 1 blk/CU x 512thr
// = 2 waves/SIMD (vs 4 in R4/R15/R16). Last untested cell: 64 MB staged AND 4 w/SIMD.
// R18 = BM=BN=128, 1024-thr block (16 waves, 4/SIMD at 1 blk/CU), proven one-barrier
// dbuf pipeline, per-wave shape identical to R4 (32x32 band, acc[2][2], 8 ds:8 MFMA).
// LDS 64 KB exact (XOR-granule swizzle, no pad). Ledger: scattered direct-frag loads
// +16us (R8/R12); grid.sync ~100us (R11); single-buffered W chunks A~17us (R13/R14).
#define BM 128
#define BN 128
#define BK 64
#define NSTEP (DD/BK)   // 4

__device__ __forceinline__ float fast_tanh(float x) {
    float e = __expf(2.0f * x);
    return 1.0f - 2.0f * __builtin_amdgcn_rcpf(e + 1.0f);
}

__device__ __forceinline__ unsigned pack2_bf16(float a, float b) {
    return (__float_as_uint(a) >> 16) | (__float_as_uint(b) & 0xFFFF0000u);
}

__device__ __forceinline__ unsigned char f32_to_fp8(float v) {
    return (unsigned char)(__builtin_amdgcn_cvt_pk_fp8_f32(v, v, 0, false) & 0xFF);
}

__global__ __launch_bounds__(1024, 4) void gemm_tanh_kernel(
    const float* __restrict__ x, const float* __restrict__ W1,
    const float* __restrict__ b1, unsigned char* __restrict__ table)
{
    // 128 rows x 64 ushorts (128 B) per buffer, XOR-swizzled granules, no padding.
    __shared__ __align__(16) unsigned short xs[2][BM * 64];   // 32 KB (reused as scratch)
    __shared__ __align__(16) unsigned short wsb[2][BN * 64];  // 32 KB

    const int tid  = threadIdx.x;
    const int bx   = blockIdx.x;
    // decode: bx = g*16 + n*8 + x -> the 2 n-siblings of a token group are 8 apart
    const int tokgrp = ((bx >> 4) << 3) | (bx & 7);   // 0..127
    const int nblk   = (bx >> 3) & 1;                 // 0..1
    const int tok0 = tokgrp * BM;
    const int n0   = nblk * BN;

    // re-zero padding row 0 (256 fp8 bytes); ws is re-poisoned before every launch
    if (bx == 0 && tid < 64) ((unsigned int*)table)[tid] = 0u;

    const int wave = tid >> 6, lane = tid & 63;
    const int wm = wave >> 2;        // 0..3: 32-row m band
    const int wn = wave & 3;         // 0..3: 32-col n band
    const int lr = lane & 15;
    const int kg = lane >> 4;
    const int sw = lr & 7;           // swizzle key == (row&7) for all frag rows this lane reads

    f32x4 xr[2], wr[2];              // staging registers (2 each at 1024 threads)

    auto load_chunk = [&](int k0) {
        #pragma unroll
        for (int rep = 0; rep < 2; ++rep) {            // x: 128 rows x 16 f32x4 = 2048 slots
            int slot = rep * 1024 + tid;
            int row = slot >> 4, kc = slot & 15;
            xr[rep] = *(const f32x4*)&x[(size_t)(tok0 + row) * DD + k0 + kc * 4];
        }
        #pragma unroll
        for (int rep = 0; rep < 2; ++rep) {            // W1: 128 rows x 16 f32x4 = 2048 slots
            int slot = rep * 1024 + tid;
            int row = slot >> 4, kc = slot & 15;
            wr[rep] = *(const f32x4*)&W1[(size_t)(n0 + row) * DD + k0 + kc * 4];
        }
    };
    auto store_lds = [&](int buf) {
        #pragma unroll
        for (int rep = 0; rep < 2; ++rep) {
            int slot = rep * 1024 + tid;
            int row = slot >> 4, kc = slot & 15;
            uint2 p;
            p.x = pack2_bf16(xr[rep].x, xr[rep].y);
            p.y = pack2_bf16(xr[rep].z, xr[rep].w);
            int gp = (kc >> 1) ^ (row & 7);            // XOR-swizzled 16B granule (0..7)
            *(uint2*)&xs[buf][row * 64 + gp * 8 + (kc & 1) * 4] = p;
        }
        #pragma unroll
        for (int rep = 0; rep < 2; ++rep) {
            int slot = rep * 1024 + tid;
            int row = slot >> 4, kc = slot & 15;
            uint2 p;
            p.x = pack2_bf16(wr[rep].x, wr[rep].y);
            p.y = pack2_bf16(wr[rep].z, wr[rep].w);
            int gp = (kc >> 1) ^ (row & 7);
            *(uint2*)&wsb[buf][row * 64 + gp * 8 + (kc & 1) * 4] = p;
        }
    };

    f32x4 acc[2][2];
    #pragma unroll
    for (int mf = 0; mf < 2; ++mf)
        #pragma unroll
        for (int nf = 0; nf < 2; ++nf)
            acc[mf][nf] = (f32x4){0.f, 0.f, 0.f, 0.f};

    load_chunk(0);
    store_lds(0);

    for (int s = 0; s < NSTEP; ++s) {
        __syncthreads();                               // one barrier per step
        const int buf = s & 1;
        if (s + 1 < NSTEP) load_chunk((s + 1) * BK);   // global loads in flight early

        #pragma unroll
        for (int c = 0; c < 2; ++c) {
            int gp8 = ((c * 4 + kg) ^ sw) * 8;
            bf16x8 af[2], bfr[2];
            #pragma unroll
            for (int mf = 0; mf < 2; ++mf) {
                int m = wm * 32 + mf * 16 + lr;
                af[mf] = *(const bf16x8*)&xs[buf][m * 64 + gp8];
            }
            #pragma unroll
            for (int nf = 0; nf < 2; ++nf) {
                int n = wn * 32 + nf * 16 + lr;
                bfr[nf] = *(const bf16x8*)&wsb[buf][n * 64 + gp8];
            }
            #pragma unroll
            for (int mf = 0; mf < 2; ++mf)
                #pragma unroll
                for (int nf = 0; nf < 2; ++nf)
                    acc[mf][nf] = __builtin_amdgcn_mfma_f32_16x16x32_bf16(
                        af[mf], bfr[nf], acc[mf][nf], 0, 0, 0);
        }
        if (s + 1 < NSTEP) store_lds(buf ^ 1);         // buf^1 reads drained at this step's barrier
    }

    // ---- epilogue: bias + tanh -> fp8, LDS transpose, coalesced stores ----
    float bj[2];
    #pragma unroll
    for (int nf = 0; nf < 2; ++nf) bj[nf] = b1[n0 + wn * 32 + nf * 16 + lr];

    __syncthreads();                                   // safe to reuse xs as scratch
    unsigned char* sc = (unsigned char*)&xs[0][0];     // [128][136] fp8 scratch (17.4 KB)
    #pragma unroll
    for (int mf = 0; mf < 2; ++mf) {
        #pragma unroll
        for (int r = 0; r < 4; ++r) {
            int m = wm * 32 + mf * 16 + kg * 4 + r;    // C/D layout: col=lane&15, row=kg*4+reg
            #pragma unroll
            for (int nf = 0; nf < 2; ++nf) {
                float v = fast_tanh(acc[mf][nf][r] + bj[nf]);
                sc[m * 136 + wn * 32 + nf * 16 + lr] = f32_to_fp8(v);
            }
        }
    }
    __syncthreads();
    {
        int row = tid >> 3;                            // 128 rows x 128 B, 16 B per thread
        int off = (tid & 7) * 16;
        uint4 v = *(const uint4*)&sc[row * 136 + off];
        *(uint4*)&table[(size_t)(1 + tok0 + row) * DD + n0 + off] = v;
    }
}

// ---------------- Kernel B: fp8 gather + max over F + dot(w2) + bias + mask ----------------
// R14-verified: 2048 blocks; each wave handles TWO tokens with all 8 gather loads
// interleaved -> 2x memory-level parallelism, half the block count.
__global__ __launch_bounds__(256) void gather_score_kernel(
    const unsigned char* __restrict__ table,
    const int* __restrict__ select_idx,
    const int* __restrict__ word_mask,
    const float* __restrict__ w2,
    const float* __restrict__ b2,
    float* __restrict__ out)
{
    const int tid  = threadIdx.x;
    const int lane = tid & 63;
    const int wv   = tid >> 6;
    const int iA   = blockIdx.x * 8 + wv * 2;     // tokens iA, iA+1
    const int iB   = iA + 1;
    const int half = lane >> 5;
    const int c    = lane & 31;
    const int d0   = c * 8;                        // 8 dims (8 B) per lane

    const int4* spA = (const int4*)(select_idx + (size_t)iA * FF);
    const int4* spB = (const int4*)(select_idx + (size_t)iB * FF);
    int4 qa0 = spA[0], qa1 = spA[1];
    int4 qb0 = spB[0], qb1 = spB[1];
    int rA[4], rB[4];
    rA[0] = half ? qa0.y : qa0.x;  rA[1] = half ? qa0.w : qa0.z;
    rA[2] = half ? qa1.y : qa1.x;  rA[3] = half ? qa1.w : qa1.z;
    rB[0] = half ? qb0.y : qb0.x;  rB[1] = half ? qb0.w : qb0.z;
    rB[2] = half ? qb1.y : qb1.x;  rB[3] = half ? qb1.w : qb1.z;

    uint2 uA[4], uB[4];                            // all 8 gathers in flight together
    #pragma unroll
    for (int it = 0; it < 4; ++it) {
        uA[it] = *(const uint2*)(table + (size_t)rA[it] * DD + d0);
        uB[it] = *(const uint2*)(table + (size_t)rB[it] * DD + d0);
    }

    float mA[8], mB[8];
    #pragma unroll
    for (int j = 0; j < 8; ++j) { mA[j] = -INFINITY; mB[j] = -INFINITY; }

    #pragma unroll
    for (int it = 0; it < 4; ++it) {
        f32x2 a0 = __builtin_amdgcn_cvt_pk_f32_fp8(uA[it].x, false);
        f32x2 a1 = __builtin_amdgcn_cvt_pk_f32_fp8(uA[it].x, true);
        f32x2 a2 = __builtin_amdgcn_cvt_pk_f32_fp8(uA[it].y, false);
        f32x2 a3 = __builtin_amdgcn_cvt_pk_f32_fp8(uA[it].y, true);
        mA[0] = fmaxf(mA[0], a0.x); mA[1] = fmaxf(mA[1], a0.y);
        mA[2] = fmaxf(mA[2], a1.x); mA[3] = fmaxf(mA[3], a1.y);
        mA[4] = fmaxf(mA[4], a2.x); mA[5] = fmaxf(mA[5], a2.y);
        mA[6] = fmaxf(mA[6], a3.x); mA[7] = fmaxf(mA[7], a3.y);
        f32x2 b0 = __builtin_amdgcn_cvt_pk_f32_fp8(uB[it].x, false);
        f32x2 b1v = __builtin_amdgcn_cvt_pk_f32_fp8(uB[it].x, true);
        f32x2 b2v = __builtin_amdgcn_cvt_pk_f32_fp8(uB[it].y, false);
        f32x2 b3 = __builtin_amdgcn_cvt_pk_f32_fp8(uB[it].y, true);
        mB[0] = fmaxf(mB[0], b0.x); mB[1] = fmaxf(mB[1], b0.y);
        mB[2] = fmaxf(mB[2], b1v.x); mB[3] = fmaxf(mB[3], b1v.y);
        mB[4] = fmaxf(mB[4], b2v.x); mB[5] = fmaxf(mB[5], b2v.y);
        mB[6] = fmaxf(mB[6], b3.x); mB[7] = fmaxf(mB[7], b3.y);
    }

    #pragma unroll
    for (int j = 0; j < 8; ++j) {
        mA[j] = fmaxf(mA[j], __shfl_xor(mA[j], 32));
        mB[j] = fmaxf(mB[j], __shfl_xor(mB[j], 32));
    }

    f32x4 wa = *(const f32x4*)&w2[d0];
    f32x4 wb = *(const f32x4*)&w2[d0 + 4];
    float pA = mA[0] * wa.x + mA[1] * wa.y + mA[2] * wa.z + mA[3] * wa.w
             + mA[4] * wb.x + mA[5] * wb.y + mA[6] * wb.z + mA[7] * wb.w;
    float pB = mB[0] * wa.x + mB[1] * wa.y + mB[2] * wa.z + mB[3] * wa.w
             + mB[4] * wb.x + mB[5] * wb.y + mB[6] * wb.z + mB[7] * wb.w;

    #pragma unroll
    for (int off = 16; off; off >>= 1) {
        pA += __shfl_xor(pA, off);
        pB += __shfl_xor(pB, off);
    }

    if (lane == 0) {
        float negA = word_mask[iA] ? 0.f : -10000.f;
        float negB = word_mask[iB] ? 0.f : -10000.f;
        out[iA] = pA + b2[0] + negA;
        out[iB] = pB + b2[0] + negB;
    }
}

extern "C" void kernel_launch(void* const* d_in, const int* in_sizes, int n_in,
                              void* d_out, int out_size, void* d_ws, size_t ws_size,
                              hipStream_t stream) {
    const float* hs    = (const float*)d_in[0];   // [B,S,D] f32
    const int*   sidx  = (const int*)  d_in[1];   // [B,S,F] i32
    const int*   wmask = (const int*)  d_in[2];   // [B,S]   i32
    const float* W1    = (const float*)d_in[3];   // [D,D]   f32
    const float* b1    = (const float*)d_in[4];   // [D]     f32
    const float* w2    = (const float*)d_in[5];   // [D]     f32
    const float* b2    = (const float*)d_in[6];   // [1]     f32
    float* out = (float*)d_out;                   // [B,S]   f32

    unsigned char* table = (unsigned char*)d_ws;  // [1+NTOK, D] fp8 e4m3 (~4.2 MB)

    gemm_tanh_kernel<<<(NTOK / BM) * (DD / BN), 1024, 0, stream>>>(hs, W1, b1, table);
    gather_score_kernel<<<NTOK / 8, 256, 0, stream>>>(table, sidx, wmask, w2, b2, out);
}